// Round 6
// baseline (411.948 us; speedup 1.0000x reference)
//
#include <hip/hip_runtime.h>
#include <hip/hip_bf16.h>

#define DD 512
#define BM 64
#define THREADS 512

typedef __attribute__((ext_vector_type(8))) short short8;   // 8 bf16 = 4 VGPRs (MFMA A/B frag)
typedef __attribute__((ext_vector_type(4))) float f32x4;    // MFMA C/D frag

__device__ __forceinline__ unsigned short f2bf(float f) {
  union { float f; unsigned u; } v; v.f = f;
  unsigned r = v.u + 0x7FFFu + ((v.u >> 16) & 1u);  // RNE
  return (unsigned short)(r >> 16);
}

// Pack kernel (K x N fp32, row-major) into MFMA-fragment-major bf16:
//   Bpack[((nb*16 + kt)*64 + lane)*8 + j]  holds  B[k][n]
//   with n = nb*16 + (lane&15), k = kt*32 + (lane>>4)*8 + j.
__global__ void prep_bpack(const float* __restrict__ W, unsigned short* __restrict__ Bpack) {
  const int tid = blockIdx.x * blockDim.x + threadIdx.x;   // 262144 threads
  const int n = tid & 511, k = tid >> 9;
  const float w = W[(size_t)k * DD + n];                   // coalesced read
  const int nb = n >> 4, lo = n & 15;
  const int kt = k >> 5, hi = (k >> 3) & 3, j = k & 7;
  const int lane = hi * 16 + lo;
  Bpack[(((size_t)(nb * 16 + kt)) * 64 + lane) * 8 + j] = f2bf(w);
}

// Fused: LN -> relu -> bf16 -> GEMM(Bpack) -> +x +bias.
// Block = 64 rows x 512 cols, 8 waves each own a 64x64 strip (16 MFMA per kt
// per wave -> B-load latency covered by MFMA issue at 4 waves/SIMD).
__global__ __launch_bounds__(THREADS, 4)   // cap ~128 regs, 2 blocks/CU
void fused_ln_gemm(const float* __restrict__ x, const float* __restrict__ lns,
                   const float* __restrict__ lnb, const unsigned short* __restrict__ Bpack,
                   const float* __restrict__ bias, float* __restrict__ out) {
  __shared__ unsigned short Alds[BM * 512];   // 64 KB, XOR-swizzled rows

  const int t = threadIdx.x;
  const int lane = t & 63, lo = lane & 15, hi = lane >> 4;
  const int wn = t >> 6;                      // wave's 64-col strip
  const long row0 = (long)blockIdx.x * BM;

  // ---------------- phase 1: LN + relu, 16 threads/row, 2 passes --------
  #pragma unroll
  for (int m2 = 0; m2 < 2; ++m2) {
    const int r = m2 * 32 + (t >> 4), g = t & 15;
    const float* xr = x + (row0 + r) * DD + g * 4;
    float4 v[8];
    float s = 0.f, s2 = 0.f;
    #pragma unroll
    for (int i = 0; i < 8; ++i) {
      v[i] = *(const float4*)(xr + i * 64);
      s  += (v[i].x + v[i].y) + (v[i].z + v[i].w);
      s2 += v[i].x * v[i].x + v[i].y * v[i].y + v[i].z * v[i].z + v[i].w * v[i].w;
    }
    #pragma unroll
    for (int m = 1; m < 16; m <<= 1) {   // 16-lane group reduce (within wave)
      s  += __shfl_xor(s,  m, 64);
      s2 += __shfl_xor(s2, m, 64);
    }
    const float mu   = s * (1.f / 512.f);
    const float var  = fmaxf(s2 * (1.f / 512.f) - mu * mu, 0.f);
    const float rstd = rsqrtf(var + 1e-6f);
    #pragma unroll
    for (int i = 0; i < 8; ++i) {
      const int c = g * 4 + i * 64;
      const float4 sc = *(const float4*)(lns + c);
      const float4 bi = *(const float4*)(lnb + c);
      ushort4 hu;
      hu.x = f2bf(fmaxf((v[i].x - mu) * rstd * sc.x + bi.x, 0.f));
      hu.y = f2bf(fmaxf((v[i].y - mu) * rstd * sc.y + bi.y, 0.f));
      hu.z = f2bf(fmaxf((v[i].z - mu) * rstd * sc.z + bi.z, 0.f));
      hu.w = f2bf(fmaxf((v[i].w - mu) * rstd * sc.w + bi.w, 0.f));
      const unsigned a = (unsigned)(r * 1024 + g * 8 + i * 128) ^ (unsigned)((r & 7) << 4);
      *(ushort4*)((char*)Alds + a) = hu;
    }
  }

  // ---------------- phase 2: acc = x + bias (C/D layout, L2-hot) --------
  // Issued BEFORE the barrier so the loads are in flight during the drain.
  const float bv0 = bias[wn * 64 +  0 + lo];
  const float bv1 = bias[wn * 64 + 16 + lo];
  const float bv2 = bias[wn * 64 + 32 + lo];
  const float bv3 = bias[wn * 64 + 48 + lo];

  f32x4 acc[4][4];
  {
    const float* xc = x + (row0 + hi * 4) * DD + wn * 64 + lo;
    #pragma unroll
    for (int m = 0; m < 4; ++m) {
      #pragma unroll
      for (int q = 0; q < 4; ++q) {
        const float* r = xc + (m * 16 + q) * DD;
        acc[m][0][q] = r[ 0] + bv0;
        acc[m][1][q] = r[16] + bv1;
        acc[m][2][q] = r[32] + bv2;
        acc[m][3][q] = r[48] + bv3;
      }
    }
  }
  __syncthreads();

  // ---------------- phase 3: GEMM (no barriers in K-loop) ---------------
  unsigned abase[4], aswz[4];
  #pragma unroll
  for (int m = 0; m < 4; ++m) {
    const int r = m * 16 + lo;
    abase[m] = (unsigned)(r * 1024 + hi * 16);
    aswz[m]  = (unsigned)((r & 7) << 4);
  }
  const short8* bbase = (const short8*)Bpack + (size_t)wn * 4096 + lane;

  #pragma unroll
  for (int kt = 0; kt < 16; ++kt) {
    const short8 b0 = bbase[0 * 1024 + kt * 64];
    const short8 b1 = bbase[1 * 1024 + kt * 64];
    const short8 b2 = bbase[2 * 1024 + kt * 64];
    const short8 b3 = bbase[3 * 1024 + kt * 64];
    short8 a[4];
    #pragma unroll
    for (int m = 0; m < 4; ++m)
      a[m] = *(const short8*)((const char*)Alds + ((abase[m] + (unsigned)kt * 64) ^ aswz[m]));
    #pragma unroll
    for (int m = 0; m < 4; ++m) {
      acc[m][0] = __builtin_amdgcn_mfma_f32_16x16x32_bf16(a[m], b0, acc[m][0], 0, 0, 0);
      acc[m][1] = __builtin_amdgcn_mfma_f32_16x16x32_bf16(a[m], b1, acc[m][1], 0, 0, 0);
      acc[m][2] = __builtin_amdgcn_mfma_f32_16x16x32_bf16(a[m], b2, acc[m][2], 0, 0, 0);
      acc[m][3] = __builtin_amdgcn_mfma_f32_16x16x32_bf16(a[m], b3, acc[m][3], 0, 0, 0);
    }
  }

  // ---------------- epilogue: pure store --------------------------------
  float* oc = out + (row0 + hi * 4) * DD + wn * 64 + lo;
  #pragma unroll
  for (int m = 0; m < 4; ++m) {
    #pragma unroll
    for (int q = 0; q < 4; ++q) {
      float* r = oc + (m * 16 + q) * DD;
      r[ 0] = acc[m][0][q];
      r[16] = acc[m][1][q];
      r[32] = acc[m][2][q];
      r[48] = acc[m][3][q];
    }
  }
}

extern "C" void kernel_launch(void* const* d_in, const int* in_sizes, int n_in,
                              void* d_out, int out_size, void* d_ws, size_t ws_size,
                              hipStream_t stream) {
  const float* x    = (const float*)d_in[0];
  const float* lns  = (const float*)d_in[1];
  const float* lnb  = (const float*)d_in[2];
  const float* W    = (const float*)d_in[3];
  const float* bias = (const float*)d_in[4];
  float* out = (float*)d_out;
  unsigned short* Bpack = (unsigned short*)d_ws;   // 512KB scratch

  const int nrows = in_sizes[0] / DD;

  prep_bpack<<<DD * DD / 256, 256, 0, stream>>>(W, Bpack);
  fused_ln_gemm<<<nrows / BM, THREADS, 0, stream>>>(x, lns, lnb, Bpack, bias, out);
}

// Round 7
// 391.753 us; speedup vs baseline: 1.0516x; 1.0516x over previous
//
#include <hip/hip_runtime.h>
#include <hip/hip_bf16.h>

#define DD 512
#define BM 32
#define THREADS 1024

typedef __attribute__((ext_vector_type(8))) short short8;   // 8 bf16 = 4 VGPRs (MFMA A/B frag)
typedef __attribute__((ext_vector_type(4))) float f32x4;    // MFMA C/D frag

__device__ __forceinline__ unsigned short f2bf(float f) {
  union { float f; unsigned u; } v; v.f = f;
  unsigned r = v.u + 0x7FFFu + ((v.u >> 16) & 1u);  // RNE
  return (unsigned short)(r >> 16);
}

// Pack kernel (K x N fp32, row-major) into MFMA-fragment-major bf16:
//   Bpack[((nb*16 + kt)*64 + lane)*8 + j]  holds  B[k][n]
//   with n = nb*16 + (lane&15), k = kt*32 + (lane>>4)*8 + j.
__global__ void prep_bpack(const float* __restrict__ W, unsigned short* __restrict__ Bpack) {
  const int tid = blockIdx.x * blockDim.x + threadIdx.x;   // 262144 threads
  const int n = tid & 511, k = tid >> 9;
  const float w = W[(size_t)k * DD + n];                   // coalesced read
  const int nb = n >> 4, lo = n & 15;
  const int kt = k >> 5, hi = (k >> 3) & 3, j = k & 7;
  const int lane = hi * 16 + lo;
  Bpack[(((size_t)(nb * 16 + kt)) * 64 + lane) * 8 + j] = f2bf(w);
}

// Fused: LN -> relu -> bf16 -> GEMM(Bpack) -> +x +bias.
// Block = 32 rows x 512 cols, 1024 threads = 16 waves; wave w owns a 32x32
// output sub-tile (cols w*32..w*32+31). Small per-thread state (acc = 16 regs)
// keeps total regs <= 64 -> 8 waves/SIMD -> 2 blocks/CU -> 100% occupancy.
__global__ __launch_bounds__(THREADS, 8)
void fused_ln_gemm(const float* __restrict__ x, const float* __restrict__ lns,
                   const float* __restrict__ lnb, const unsigned short* __restrict__ Bpack,
                   const float* __restrict__ bias, float* __restrict__ out) {
  __shared__ unsigned short Alds[BM * 512];   // 32 KB, XOR-swizzled rows

  const int t = threadIdx.x;
  const int lane = t & 63, lo = lane & 15, hi = lane >> 4;
  const int w = t >> 6;                       // wave id 0..15 -> 32-col strip
  const long row0 = (long)blockIdx.x * BM;

  // ---------------- phase 1: LN + relu, 32 threads per row --------------
  {
    const int r = t >> 5, g = t & 31;         // lanes 0-31 / 32-63 = 2 rows/wave
    const float* xr = x + (row0 + r) * DD + g * 4;
    float4 v[4];
    float s = 0.f, s2 = 0.f;
    #pragma unroll
    for (int i = 0; i < 4; ++i) {
      v[i] = *(const float4*)(xr + i * 128);
      s  += (v[i].x + v[i].y) + (v[i].z + v[i].w);
      s2 += v[i].x * v[i].x + v[i].y * v[i].y + v[i].z * v[i].z + v[i].w * v[i].w;
    }
    #pragma unroll
    for (int m = 1; m < 32; m <<= 1) {   // 32-lane group reduce (stays in half-wave)
      s  += __shfl_xor(s,  m, 64);
      s2 += __shfl_xor(s2, m, 64);
    }
    const float mu   = s * (1.f / 512.f);
    const float var  = fmaxf(s2 * (1.f / 512.f) - mu * mu, 0.f);
    const float rstd = rsqrtf(var + 1e-6f);
    #pragma unroll
    for (int i = 0; i < 4; ++i) {
      const int c = g * 4 + i * 128;
      const float4 sc = *(const float4*)(lns + c);
      const float4 bi = *(const float4*)(lnb + c);
      ushort4 hu;
      hu.x = f2bf(fmaxf((v[i].x - mu) * rstd * sc.x + bi.x, 0.f));
      hu.y = f2bf(fmaxf((v[i].y - mu) * rstd * sc.y + bi.y, 0.f));
      hu.z = f2bf(fmaxf((v[i].z - mu) * rstd * sc.z + bi.z, 0.f));
      hu.w = f2bf(fmaxf((v[i].w - mu) * rstd * sc.w + bi.w, 0.f));
      // byte addr (r*1024 + c*2) ^ ((r&7)<<4) — 8B-aligned stays 8B-aligned
      const unsigned a = (unsigned)(r * 1024 + g * 8 + i * 256) ^ (unsigned)((r & 7) << 4);
      *(ushort4*)((char*)Alds + a) = hu;
    }
  }

  // ---------------- phase 2: acc = x + bias (C/D layout, L2-hot) --------
  // Issued BEFORE the barrier so loads are in flight during the LDS drain.
  const int col0 = w * 32 + lo;
  const float bv0 = bias[col0];
  const float bv1 = bias[col0 + 16];

  f32x4 acc00, acc01, acc10, acc11;           // [m][nt], m-row tiles 0/16
  {
    const float* xc = x + (row0 + hi * 4) * DD + col0;
    #pragma unroll
    for (int q = 0; q < 4; ++q) {
      const float* r0 = xc + q * DD;           // rows hi*4+q
      const float* r1 = xc + 16 * DD + q * DD; // rows 16+hi*4+q
      acc00[q] = r0[0]  + bv0;
      acc01[q] = r0[16] + bv1;
      acc10[q] = r1[0]  + bv0;
      acc11[q] = r1[16] + bv1;
    }
  }
  __syncthreads();

  // ---------------- phase 3: GEMM (no barriers in K-loop) ---------------
  const unsigned ab0 = (unsigned)(lo * 1024 + hi * 16);
  const unsigned ab1 = (unsigned)((16 + lo) * 1024 + hi * 16);
  const unsigned asw = (unsigned)((lo & 7) << 4);   // (16+lo)&7 == lo&7
  // B frag (nb = w*2 + nt, kt): Bpack8 + (nb*16 + kt)*64 + lane
  const short8* bb = (const short8*)Bpack + (size_t)(w * 2) * 1024 + lane;

  #pragma unroll
  for (int kt = 0; kt < 16; ++kt) {
    const short8 b0 = bb[kt * 64];
    const short8 b1 = bb[1024 + kt * 64];
    const short8 a0 = *(const short8*)((const char*)Alds + ((ab0 + (unsigned)kt * 64) ^ asw));
    const short8 a1 = *(const short8*)((const char*)Alds + ((ab1 + (unsigned)kt * 64) ^ asw));
    acc00 = __builtin_amdgcn_mfma_f32_16x16x32_bf16(a0, b0, acc00, 0, 0, 0);
    acc01 = __builtin_amdgcn_mfma_f32_16x16x32_bf16(a0, b1, acc01, 0, 0, 0);
    acc10 = __builtin_amdgcn_mfma_f32_16x16x32_bf16(a1, b0, acc10, 0, 0, 0);
    acc11 = __builtin_amdgcn_mfma_f32_16x16x32_bf16(a1, b1, acc11, 0, 0, 0);
  }

  // ---------------- epilogue: pure store --------------------------------
  float* oc = out + (row0 + hi * 4) * DD + col0;
  #pragma unroll
  for (int q = 0; q < 4; ++q) {
    float* r0 = oc + q * DD;
    float* r1 = oc + 16 * DD + q * DD;
    r0[0]  = acc00[q];
    r0[16] = acc01[q];
    r1[0]  = acc10[q];
    r1[16] = acc11[q];
  }
}

extern "C" void kernel_launch(void* const* d_in, const int* in_sizes, int n_in,
                              void* d_out, int out_size, void* d_ws, size_t ws_size,
                              hipStream_t stream) {
  const float* x    = (const float*)d_in[0];
  const float* lns  = (const float*)d_in[1];
  const float* lnb  = (const float*)d_in[2];
  const float* W    = (const float*)d_in[3];
  const float* bias = (const float*)d_in[4];
  float* out = (float*)d_out;
  unsigned short* Bpack = (unsigned short*)d_ws;   // 512KB scratch

  const int nrows = in_sizes[0] / DD;

  prep_bpack<<<DD * DD / 256, 256, 0, stream>>>(W, Bpack);
  fused_ln_gemm<<<nrows / BM, THREADS, 0, stream>>>(x, lns, lnb, Bpack, bias, out);
}

// Round 8
// 313.957 us; speedup vs baseline: 1.3121x; 1.2478x over previous
//
#include <hip/hip_runtime.h>
#include <hip/hip_bf16.h>

#define DD 512
#define BM 32
#define THREADS 512

typedef __attribute__((ext_vector_type(8))) short short8;   // 8 bf16 = 4 VGPRs (MFMA A/B frag)
typedef __attribute__((ext_vector_type(4))) float f32x4;    // MFMA C/D frag

__device__ __forceinline__ unsigned short f2bf(float f) {
  union { float f; unsigned u; } v; v.f = f;
  unsigned r = v.u + 0x7FFFu + ((v.u >> 16) & 1u);  // RNE
  return (unsigned short)(r >> 16);
}
__device__ __forceinline__ float bf2f(unsigned short u) {
  union { unsigned u; float f; } v; v.u = ((unsigned)u) << 16;
  return v.f;
}

// Pack kernel (K x N fp32, row-major) into MFMA-fragment-major bf16:
//   Bpack[((nb*16 + kt)*64 + lane)*8 + j]  holds  B[k][n]
//   with n = nb*16 + (lane&15), k = kt*32 + (lane>>4)*8 + j.
__global__ void prep_bpack(const float* __restrict__ W, unsigned short* __restrict__ Bpack) {
  const int tid = blockIdx.x * blockDim.x + threadIdx.x;   // 262144 threads
  const int n = tid & 511, k = tid >> 9;
  const float w = W[(size_t)k * DD + n];                   // coalesced read
  const int nb = n >> 4, lo = n & 15;
  const int kt = k >> 5, hi = (k >> 3) & 3, j = k & 7;
  const int lane = hi * 16 + lo;
  Bpack[(((size_t)(nb * 16 + kt)) * 64 + lane) * 8 + j] = f2bf(w);
}

// Fused: LN -> relu -> (bf16 cast) -> GEMM vs Bpack -> +x +bias
// R3 structure + sched_barrier-pinned depth-3 B prefetch ring.
__global__ __launch_bounds__(THREADS, 4)
void fused_ln_gemm(const float* __restrict__ x, const float* __restrict__ lns,
                   const float* __restrict__ lnb, const unsigned short* __restrict__ Bpack,
                   const float* __restrict__ bias, float* __restrict__ out) {
  __shared__ unsigned short Alds[BM * 512];   // h bf16, XOR-swizzled rows (1KB row)
  __shared__ unsigned short Xlds[BM * 528];   // x bf16, padded stride (1056B row)

  const int t = threadIdx.x;
  const long row0 = (long)blockIdx.x * BM;

  // ---------------- LN + relu phase: 16 threads per row ----------------
  {
    const int r = t >> 4, g = t & 15;
    const float* xr = x + (row0 + r) * DD + g * 4;
    float4 v[8];
    float s = 0.f, s2 = 0.f;
    #pragma unroll
    for (int i = 0; i < 8; ++i) {
      v[i] = *(const float4*)(xr + i * 64);
      s  += (v[i].x + v[i].y) + (v[i].z + v[i].w);
      s2 += v[i].x * v[i].x + v[i].y * v[i].y + v[i].z * v[i].z + v[i].w * v[i].w;
    }
    #pragma unroll
    for (int m = 1; m < 16; m <<= 1) {   // 16-lane group reduce (within wave)
      s  += __shfl_xor(s,  m, 64);
      s2 += __shfl_xor(s2, m, 64);
    }
    const float mu   = s * (1.f / 512.f);
    const float var  = fmaxf(s2 * (1.f / 512.f) - mu * mu, 0.f);
    const float rstd = rsqrtf(var + 1e-6f);
    #pragma unroll
    for (int i = 0; i < 8; ++i) {
      const int c = g * 4 + i * 64;
      const float4 sc = *(const float4*)(lns + c);
      const float4 bi = *(const float4*)(lnb + c);
      float h0 = fmaxf((v[i].x - mu) * rstd * sc.x + bi.x, 0.f);
      float h1 = fmaxf((v[i].y - mu) * rstd * sc.y + bi.y, 0.f);
      float h2 = fmaxf((v[i].z - mu) * rstd * sc.z + bi.z, 0.f);
      float h3 = fmaxf((v[i].w - mu) * rstd * sc.w + bi.w, 0.f);
      ushort4 hu = { f2bf(h0), f2bf(h1), f2bf(h2), f2bf(h3) };
      ushort4 xu = { f2bf(v[i].x), f2bf(v[i].y), f2bf(v[i].z), f2bf(v[i].w) };
      // A: byte addr (r*1024 + c*2) ^ ((r&7)<<4)  — 8B-aligned stays 8B-aligned
      unsigned a = (unsigned)(r * 1024 + g * 8 + i * 128) ^ (unsigned)((r & 7) << 4);
      *(ushort4*)((char*)Alds + a) = hu;
      *(ushort4*)(&Xlds[r * 528 + c]) = xu;
    }
  }
  __syncthreads();

  // ------- GEMM phase: pinned depth-3 B ring, no barriers in K-loop -----
  const int lane = t & 63, lo = lane & 15, hi = lane >> 4;
  const int wn = t >> 6;                       // 0..7: wave's 64-col strip

  unsigned abase0, aswz0, abase1, aswz1;
  {
    const int r0 = lo;        abase0 = (unsigned)(r0 * 1024 + hi * 16); aswz0 = (unsigned)((r0 & 7) << 4);
    const int r1 = 16 + lo;   abase1 = (unsigned)(r1 * 1024 + hi * 16); aswz1 = (unsigned)((r1 & 7) << 4);
  }
  // B frag (nb = wn*4 + nt, kt): Bpack8 + (nb*16 + kt)*64 + lane  (16B units)
  const short8* bbase = (const short8*)Bpack + (size_t)wn * 4096 + lane;

  short8 rb[3][4];   // depth-3 prefetch ring; all indices static after unroll
#define LOADB(s, kt)                                                          \
  { rb[s][0] = bbase[(0 * 16 + (kt)) * 64];                                   \
    rb[s][1] = bbase[(1 * 16 + (kt)) * 64];                                   \
    rb[s][2] = bbase[(2 * 16 + (kt)) * 64];                                   \
    rb[s][3] = bbase[(3 * 16 + (kt)) * 64]; }

  LOADB(0, 0);
  LOADB(1, 1);
  __builtin_amdgcn_sched_barrier(0);   // pin: 8 loads issued before any MFMA

  f32x4 acc00 = {}, acc01 = {}, acc02 = {}, acc03 = {};
  f32x4 acc10 = {}, acc11 = {}, acc12 = {}, acc13 = {};

  #pragma unroll
  for (int kt = 0; kt < 16; ++kt) {
    const int cur = kt % 3;
    if (kt + 2 < 16) {
      const int nxt = (kt + 2) % 3;
      LOADB(nxt, kt + 2);                // issue kt+2's 4 loads FIRST
    }
    __builtin_amdgcn_sched_barrier(0);   // loads may not sink below this
    const short8 a0 = *(const short8*)((const char*)Alds + ((abase0 + (unsigned)kt * 64) ^ aswz0));
    const short8 a1 = *(const short8*)((const char*)Alds + ((abase1 + (unsigned)kt * 64) ^ aswz1));
    acc00 = __builtin_amdgcn_mfma_f32_16x16x32_bf16(a0, rb[cur][0], acc00, 0, 0, 0);
    acc10 = __builtin_amdgcn_mfma_f32_16x16x32_bf16(a1, rb[cur][0], acc10, 0, 0, 0);
    acc01 = __builtin_amdgcn_mfma_f32_16x16x32_bf16(a0, rb[cur][1], acc01, 0, 0, 0);
    acc11 = __builtin_amdgcn_mfma_f32_16x16x32_bf16(a1, rb[cur][1], acc11, 0, 0, 0);
    acc02 = __builtin_amdgcn_mfma_f32_16x16x32_bf16(a0, rb[cur][2], acc02, 0, 0, 0);
    acc12 = __builtin_amdgcn_mfma_f32_16x16x32_bf16(a1, rb[cur][2], acc12, 0, 0, 0);
    acc03 = __builtin_amdgcn_mfma_f32_16x16x32_bf16(a0, rb[cur][3], acc03, 0, 0, 0);
    acc13 = __builtin_amdgcn_mfma_f32_16x16x32_bf16(a1, rb[cur][3], acc13, 0, 0, 0);
  }
#undef LOADB

  // ---------------- epilogue: out = x + acc + bias ----------------
  f32x4 accs[2][4] = {{acc00, acc01, acc02, acc03}, {acc10, acc11, acc12, acc13}};
  #pragma unroll
  for (int m = 0; m < 2; ++m) {
    #pragma unroll
    for (int nt = 0; nt < 4; ++nt) {
      const int col = wn * 64 + nt * 16 + lo;
      const float bv = bias[col];
      #pragma unroll
      for (int q = 0; q < 4; ++q) {
        const int rloc = m * 16 + hi * 4 + q;      // C/D: row = 4*hi + reg
        const float xv = bf2f(Xlds[rloc * 528 + col]);
        out[(row0 + rloc) * DD + col] = xv + accs[m][nt][q] + bv;
      }
    }
  }
}

extern "C" void kernel_launch(void* const* d_in, const int* in_sizes, int n_in,
                              void* d_out, int out_size, void* d_ws, size_t ws_size,
                              hipStream_t stream) {
  const float* x    = (const float*)d_in[0];
  const float* lns  = (const float*)d_in[1];
  const float* lnb  = (const float*)d_in[2];
  const float* W    = (const float*)d_in[3];
  const float* bias = (const float*)d_in[4];
  float* out = (float*)d_out;
  unsigned short* Bpack = (unsigned short*)d_ws;   // 512KB scratch

  const int nrows = in_sizes[0] / DD;

  prep_bpack<<<DD * DD / 256, 256, 0, stream>>>(W, Bpack);
  fused_ln_gemm<<<nrows / BM, THREADS, 0, stream>>>(x, lns, lnb, Bpack, bias, out);
}

// Round 9
// 311.142 us; speedup vs baseline: 1.3240x; 1.0090x over previous
//
#include <hip/hip_runtime.h>
#include <hip/hip_bf16.h>

#define DD 512
#define BM 32
#define THREADS 512

typedef __attribute__((ext_vector_type(8))) short short8;   // 8 bf16 = 4 VGPRs (MFMA A/B frag)
typedef __attribute__((ext_vector_type(4))) float f32x4;    // MFMA C/D frag

__device__ __forceinline__ unsigned short f2bf(float f) {
  union { float f; unsigned u; } v; v.f = f;
  unsigned r = v.u + 0x7FFFu + ((v.u >> 16) & 1u);  // RNE
  return (unsigned short)(r >> 16);
}
__device__ __forceinline__ float bf2f(unsigned short u) {
  union { unsigned u; float f; } v; v.u = ((unsigned)u) << 16;
  return v.f;
}

// Pack kernel (K x N fp32, row-major) into MFMA-fragment-major bf16:
//   Bpack[((nb*16 + kt)*64 + lane)*8 + j]  holds  B[k][n]
//   with n = nb*16 + (lane&15), k = kt*32 + (lane>>4)*8 + j.
__global__ void prep_bpack(const float* __restrict__ W, unsigned short* __restrict__ Bpack) {
  const int tid = blockIdx.x * blockDim.x + threadIdx.x;   // 262144 threads
  const int n = tid & 511, k = tid >> 9;
  const float w = W[(size_t)k * DD + n];                   // coalesced read
  const int nb = n >> 4, lo = n & 15;
  const int kt = k >> 5, hi = (k >> 3) & 3, j = k & 7;
  const int lane = hi * 16 + lo;
  Bpack[(((size_t)(nb * 16 + kt)) * 64 + lane) * 8 + j] = f2bf(w);
}

// Fused: LN -> relu -> (bf16 cast) -> GEMM vs Bpack -> +x +bias
// R8 structure + sched_barrier-pinned depth-4 B prefetch ring.
__global__ __launch_bounds__(THREADS, 4)
void fused_ln_gemm(const float* __restrict__ x, const float* __restrict__ lns,
                   const float* __restrict__ lnb, const unsigned short* __restrict__ Bpack,
                   const float* __restrict__ bias, float* __restrict__ out) {
  __shared__ unsigned short Alds[BM * 512];   // h bf16, XOR-swizzled rows (1KB row)
  __shared__ unsigned short Xlds[BM * 528];   // x bf16, padded stride (1056B row)

  const int t = threadIdx.x;
  const long row0 = (long)blockIdx.x * BM;

  // ---------------- LN + relu phase: 16 threads per row ----------------
  {
    const int r = t >> 4, g = t & 15;
    const float* xr = x + (row0 + r) * DD + g * 4;
    float4 v[8];
    float s = 0.f, s2 = 0.f;
    #pragma unroll
    for (int i = 0; i < 8; ++i) {
      v[i] = *(const float4*)(xr + i * 64);
      s  += (v[i].x + v[i].y) + (v[i].z + v[i].w);
      s2 += v[i].x * v[i].x + v[i].y * v[i].y + v[i].z * v[i].z + v[i].w * v[i].w;
    }
    #pragma unroll
    for (int m = 1; m < 16; m <<= 1) {   // 16-lane group reduce (within wave)
      s  += __shfl_xor(s,  m, 64);
      s2 += __shfl_xor(s2, m, 64);
    }
    const float mu   = s * (1.f / 512.f);
    const float var  = fmaxf(s2 * (1.f / 512.f) - mu * mu, 0.f);
    const float rstd = rsqrtf(var + 1e-6f);
    #pragma unroll
    for (int i = 0; i < 8; ++i) {
      const int c = g * 4 + i * 64;
      const float4 sc = *(const float4*)(lns + c);
      const float4 bi = *(const float4*)(lnb + c);
      float h0 = fmaxf((v[i].x - mu) * rstd * sc.x + bi.x, 0.f);
      float h1 = fmaxf((v[i].y - mu) * rstd * sc.y + bi.y, 0.f);
      float h2 = fmaxf((v[i].z - mu) * rstd * sc.z + bi.z, 0.f);
      float h3 = fmaxf((v[i].w - mu) * rstd * sc.w + bi.w, 0.f);
      ushort4 hu = { f2bf(h0), f2bf(h1), f2bf(h2), f2bf(h3) };
      ushort4 xu = { f2bf(v[i].x), f2bf(v[i].y), f2bf(v[i].z), f2bf(v[i].w) };
      // A: byte addr (r*1024 + c*2) ^ ((r&7)<<4)  — 8B-aligned stays 8B-aligned
      unsigned a = (unsigned)(r * 1024 + g * 8 + i * 128) ^ (unsigned)((r & 7) << 4);
      *(ushort4*)((char*)Alds + a) = hu;
      *(ushort4*)(&Xlds[r * 528 + c]) = xu;
    }
  }
  __syncthreads();

  // ------- GEMM phase: pinned depth-4 B ring, no barriers in K-loop -----
  const int lane = t & 63, lo = lane & 15, hi = lane >> 4;
  const int wn = t >> 6;                       // 0..7: wave's 64-col strip

  unsigned abase0, aswz0, abase1, aswz1;
  {
    const int r0 = lo;        abase0 = (unsigned)(r0 * 1024 + hi * 16); aswz0 = (unsigned)((r0 & 7) << 4);
    const int r1 = 16 + lo;   abase1 = (unsigned)(r1 * 1024 + hi * 16); aswz1 = (unsigned)((r1 & 7) << 4);
  }
  // B frag (nb = wn*4 + nt, kt): Bpack8 + (nb*16 + kt)*64 + lane  (16B units)
  const short8* bbase = (const short8*)Bpack + (size_t)wn * 4096 + lane;

  short8 rb[4][4];   // depth-4 prefetch ring; all indices static after unroll
#define LOADB(s, kt)                                                          \
  { rb[s][0] = bbase[(0 * 16 + (kt)) * 64];                                   \
    rb[s][1] = bbase[(1 * 16 + (kt)) * 64];                                   \
    rb[s][2] = bbase[(2 * 16 + (kt)) * 64];                                   \
    rb[s][3] = bbase[(3 * 16 + (kt)) * 64]; }

  LOADB(0, 0);
  LOADB(1, 1);
  LOADB(2, 2);
  __builtin_amdgcn_sched_barrier(0);   // pin: 12 loads issued before any MFMA

  f32x4 acc00 = {}, acc01 = {}, acc02 = {}, acc03 = {};
  f32x4 acc10 = {}, acc11 = {}, acc12 = {}, acc13 = {};

  #pragma unroll
  for (int kt = 0; kt < 16; ++kt) {
    const int cur = kt & 3;
    if (kt + 3 < 16) {
      const int nxt = (kt + 3) & 3;
      LOADB(nxt, kt + 3);                // issue kt+3's 4 loads FIRST
    }
    __builtin_amdgcn_sched_barrier(0);   // loads may not sink below this
    const short8 a0 = *(const short8*)((const char*)Alds + ((abase0 + (unsigned)kt * 64) ^ aswz0));
    const short8 a1 = *(const short8*)((const char*)Alds + ((abase1 + (unsigned)kt * 64) ^ aswz1));
    acc00 = __builtin_amdgcn_mfma_f32_16x16x32_bf16(a0, rb[cur][0], acc00, 0, 0, 0);
    acc10 = __builtin_amdgcn_mfma_f32_16x16x32_bf16(a1, rb[cur][0], acc10, 0, 0, 0);
    acc01 = __builtin_amdgcn_mfma_f32_16x16x32_bf16(a0, rb[cur][1], acc01, 0, 0, 0);
    acc11 = __builtin_amdgcn_mfma_f32_16x16x32_bf16(a1, rb[cur][1], acc11, 0, 0, 0);
    acc02 = __builtin_amdgcn_mfma_f32_16x16x32_bf16(a0, rb[cur][2], acc02, 0, 0, 0);
    acc12 = __builtin_amdgcn_mfma_f32_16x16x32_bf16(a1, rb[cur][2], acc12, 0, 0, 0);
    acc03 = __builtin_amdgcn_mfma_f32_16x16x32_bf16(a0, rb[cur][3], acc03, 0, 0, 0);
    acc13 = __builtin_amdgcn_mfma_f32_16x16x32_bf16(a1, rb[cur][3], acc13, 0, 0, 0);
  }
#undef LOADB

  // ---------------- epilogue: out = x + acc + bias ----------------
  f32x4 accs[2][4] = {{acc00, acc01, acc02, acc03}, {acc10, acc11, acc12, acc13}};
  #pragma unroll
  for (int m = 0; m < 2; ++m) {
    #pragma unroll
    for (int nt = 0; nt < 4; ++nt) {
      const int col = wn * 64 + nt * 16 + lo;
      const float bv = bias[col];
      #pragma unroll
      for (int q = 0; q < 4; ++q) {
        const int rloc = m * 16 + hi * 4 + q;      // C/D: row = 4*hi + reg
        const float xv = bf2f(Xlds[rloc * 528 + col]);
        out[(row0 + rloc) * DD + col] = xv + accs[m][nt][q] + bv;
      }
    }
  }
}

extern "C" void kernel_launch(void* const* d_in, const int* in_sizes, int n_in,
                              void* d_out, int out_size, void* d_ws, size_t ws_size,
                              hipStream_t stream) {
  const float* x    = (const float*)d_in[0];
  const float* lns  = (const float*)d_in[1];
  const float* lnb  = (const float*)d_in[2];
  const float* W    = (const float*)d_in[3];
  const float* bias = (const float*)d_in[4];
  float* out = (float*)d_out;
  unsigned short* Bpack = (unsigned short*)d_ws;   // 512KB scratch

  const int nrows = in_sizes[0] / DD;

  prep_bpack<<<DD * DD / 256, 256, 0, stream>>>(W, Bpack);
  fused_ln_gemm<<<nrows / BM, THREADS, 0, stream>>>(x, lns, lnb, Bpack, bias, out);
}

// Round 10
// 295.372 us; speedup vs baseline: 1.3947x; 1.0534x over previous
//
#include <hip/hip_runtime.h>
#include <hip/hip_bf16.h>

#define DD 512
#define BM 64
#define THREADS 1024

typedef __attribute__((ext_vector_type(8))) short short8;   // 8 bf16 = 4 VGPRs (MFMA A/B frag)
typedef __attribute__((ext_vector_type(4))) float f32x4;    // MFMA C/D frag

__device__ __forceinline__ unsigned short f2bf(float f) {
  union { float f; unsigned u; } v; v.f = f;
  unsigned r = v.u + 0x7FFFu + ((v.u >> 16) & 1u);  // RNE
  return (unsigned short)(r >> 16);
}
__device__ __forceinline__ float bf2f(unsigned short u) {
  union { unsigned u; float f; } v; v.u = ((unsigned)u) << 16;
  return v.f;
}

// Pack kernel (K x N fp32, row-major) into MFMA-fragment-major bf16:
//   Bpack[((nb*16 + kt)*64 + lane)*8 + j]  holds  B[k][n]
//   with n = nb*16 + (lane&15), k = kt*32 + (lane>>4)*8 + j.
__global__ void prep_bpack(const float* __restrict__ W, unsigned short* __restrict__ Bpack) {
  const int tid = blockIdx.x * blockDim.x + threadIdx.x;   // 262144 threads
  const int n = tid & 511, k = tid >> 9;
  const float w = W[(size_t)k * DD + n];                   // coalesced read
  const int nb = n >> 4, lo = n & 15;
  const int kt = k >> 5, hi = (k >> 3) & 3, j = k & 7;
  const int lane = hi * 16 + lo;
  Bpack[(((size_t)(nb * 16 + kt)) * 64 + lane) * 8 + j] = f2bf(w);
}

// Fused: LN -> relu -> bf16 -> GEMM(Bpack) -> +x +bias.
// Block = 64 rows x 512 cols, 1024 threads = 16 waves; wave w owns a 64x32
// output strip (cols w*32..+31) -> each B column-strip is read by EXACTLY ONE
// wave -> block B L2 traffic = 512 KB (2 GB total, half of BM=32).
__global__ __launch_bounds__(THREADS, 4)   // 16 waves = 1 block/CU, VGPR cap 128
void fused_ln_gemm(const float* __restrict__ x, const float* __restrict__ lns,
                   const float* __restrict__ lnb, const unsigned short* __restrict__ Bpack,
                   const float* __restrict__ bias, float* __restrict__ out) {
  __shared__ unsigned short Alds[BM * 512];   // 64 KB, h bf16, XOR-swizzled rows
  __shared__ unsigned short Xlds[BM * 512];   // 64 KB, x bf16, XOR-swizzled rows

  const int t = threadIdx.x;
  const int lane = t & 63, lo = lane & 15, hi = lane >> 4;
  const int w = t >> 6;                       // wave id 0..15 -> 32-col strip
  const long row0 = (long)blockIdx.x * BM;

  // ---------------- LN + relu phase: 16 threads per row (64 rows) -------
  {
    const int r = t >> 4, g = t & 15;
    const float* xr = x + (row0 + r) * DD + g * 4;
    float4 v[8];
    float s = 0.f, s2 = 0.f;
    #pragma unroll
    for (int i = 0; i < 8; ++i) {
      v[i] = *(const float4*)(xr + i * 64);
      s  += (v[i].x + v[i].y) + (v[i].z + v[i].w);
      s2 += v[i].x * v[i].x + v[i].y * v[i].y + v[i].z * v[i].z + v[i].w * v[i].w;
    }
    #pragma unroll
    for (int m = 1; m < 16; m <<= 1) {   // 16-lane group reduce (within wave)
      s  += __shfl_xor(s,  m, 64);
      s2 += __shfl_xor(s2, m, 64);
    }
    const float mu   = s * (1.f / 512.f);
    const float var  = fmaxf(s2 * (1.f / 512.f) - mu * mu, 0.f);
    const float rstd = rsqrtf(var + 1e-6f);
    #pragma unroll
    for (int i = 0; i < 8; ++i) {
      const int c = g * 4 + i * 64;
      const float4 sc = *(const float4*)(lns + c);
      const float4 bi = *(const float4*)(lnb + c);
      ushort4 hu;
      hu.x = f2bf(fmaxf((v[i].x - mu) * rstd * sc.x + bi.x, 0.f));
      hu.y = f2bf(fmaxf((v[i].y - mu) * rstd * sc.y + bi.y, 0.f));
      hu.z = f2bf(fmaxf((v[i].z - mu) * rstd * sc.z + bi.z, 0.f));
      hu.w = f2bf(fmaxf((v[i].w - mu) * rstd * sc.w + bi.w, 0.f));
      ushort4 xu = { f2bf(v[i].x), f2bf(v[i].y), f2bf(v[i].z), f2bf(v[i].w) };
      // byte addr (r*1024 + c*2) ^ ((r&7)<<4) — 8B-aligned stays 8B-aligned
      const unsigned a = (unsigned)(r * 1024 + g * 8 + i * 128) ^ (unsigned)((r & 7) << 4);
      *(ushort4*)((char*)Alds + a) = hu;
      *(ushort4*)((char*)Xlds + a) = xu;
    }
  }
  __syncthreads();

  // ------- GEMM phase: pinned depth-3 B ring, no barriers in K-loop -----
  unsigned abase[4];
  #pragma unroll
  for (int m = 0; m < 4; ++m)
    abase[m] = (unsigned)((m * 16 + lo) * 1024 + hi * 16);
  const unsigned asw = (unsigned)((lo & 7) << 4);   // (m*16+lo)&7 == lo&7

  // B frag (nb = w*2 + nt, kt): Bpack8 + ((w*2+nt)*16 + kt)*64 + lane
  const short8* bbase = (const short8*)Bpack + (size_t)(w * 2) * 1024 + lane;

  short8 rb[3][2];   // depth-3 prefetch ring; indices static after unroll
#define LOADB(s, kt)                                                          \
  { rb[s][0] = bbase[(0 * 16 + (kt)) * 64];                                   \
    rb[s][1] = bbase[(1 * 16 + (kt)) * 64]; }

  LOADB(0, 0);
  LOADB(1, 1);
  __builtin_amdgcn_sched_barrier(0);   // pin: 4 loads issued before any MFMA

  f32x4 acc[4][2] = {};

  #pragma unroll
  for (int kt = 0; kt < 16; ++kt) {
    const int cur = kt % 3;
    if (kt + 2 < 16) {
      const int nxt = (kt + 2) % 3;
      LOADB(nxt, kt + 2);                // issue kt+2's loads FIRST
    }
    __builtin_amdgcn_sched_barrier(0);   // loads may not sink below this
    short8 a[4];
    #pragma unroll
    for (int m = 0; m < 4; ++m)
      a[m] = *(const short8*)((const char*)Alds + ((abase[m] + (unsigned)kt * 64) ^ asw));
    #pragma unroll
    for (int m = 0; m < 4; ++m) {
      acc[m][0] = __builtin_amdgcn_mfma_f32_16x16x32_bf16(a[m], rb[cur][0], acc[m][0], 0, 0, 0);
      acc[m][1] = __builtin_amdgcn_mfma_f32_16x16x32_bf16(a[m], rb[cur][1], acc[m][1], 0, 0, 0);
    }
  }
#undef LOADB

  // ---------------- epilogue: out = x + acc + bias ----------------------
  const int col0 = w * 32 + lo;
  const float bv0 = bias[col0];
  const float bv1 = bias[col0 + 16];
  #pragma unroll
  for (int m = 0; m < 4; ++m) {
    #pragma unroll
    for (int q = 0; q < 4; ++q) {
      const int rl = m * 16 + hi * 4 + q;          // C/D: row = 4*hi + reg
      const unsigned xb = (unsigned)(rl * 1024 + col0 * 2) ^ (unsigned)((rl & 7) << 4);
      const float xv0 = bf2f(*(const unsigned short*)((const char*)Xlds + xb));
      const float xv1 = bf2f(*(const unsigned short*)((const char*)Xlds + (xb ^ 32u)));  // +16 cols: bit5 flip, XOR untouched
      float* o = out + (row0 + rl) * DD + col0;
      o[0]  = acc[m][0][q] + xv0 + bv0;
      o[16] = acc[m][1][q] + xv1 + bv1;
    }
  }
}

extern "C" void kernel_launch(void* const* d_in, const int* in_sizes, int n_in,
                              void* d_out, int out_size, void* d_ws, size_t ws_size,
                              hipStream_t stream) {
  const float* x    = (const float*)d_in[0];
  const float* lns  = (const float*)d_in[1];
  const float* lnb  = (const float*)d_in[2];
  const float* W    = (const float*)d_in[3];
  const float* bias = (const float*)d_in[4];
  float* out = (float*)d_out;
  unsigned short* Bpack = (unsigned short*)d_ws;   // 512KB scratch

  const int nrows = in_sizes[0] / DD;

  prep_bpack<<<DD * DD / 256, 256, 0, stream>>>(W, Bpack);
  fused_ln_gemm<<<nrows / BM, THREADS, 0, stream>>>(x, lns, lnb, Bpack, bias, out);
}